// Round 11
// baseline (1099.199 us; speedup 1.0000x reference)
//
#include <hip/hip_runtime.h>
#include <float.h>

#define NEG 0.2f
constexpr int BATCH = 8;
constexpr int NPTS  = 2048;
constexpr int KNN   = 10;
constexpr int KP1   = 11;

__device__ __forceinline__ float lrelu(float x) { return x > 0.f ? x : NEG * x; }

// ordered-u64 key: (monotone uint of d2) << 32 | idx  => u64 '<' == (d2 asc, idx asc)
__device__ __forceinline__ unsigned long long dkey(float d, int m) {
    unsigned u = __float_as_uint(d);
    u ^= (unsigned)((int)u >> 31) | 0x80000000u;
    return ((unsigned long long)u << 32) | (unsigned)m;
}

// ---------------- squared-norm per point ----------------
template<int D>
__global__ void sq_kernel(const float* __restrict__ xt, float* __restrict__ sq) {
    int i = blockIdx.x * 256 + threadIdx.x;
    if (i >= BATCH * NPTS) return;
    const float* p = xt + (size_t)i * D;
    float s = 0.f;
    #pragma unroll
    for (int d = 0; d < D; ++d) s += p[d] * p[d];
    sq[i] = s;
}

__global__ void sq64_kernel(const float* __restrict__ xt, float* __restrict__ sq) {
    int i = blockIdx.x * 256 + threadIdx.x;
    if (i >= BATCH * NPTS) return;
    const float4* p = (const float4*)(xt + (size_t)i * 64);
    float4 s4 = {0.f, 0.f, 0.f, 0.f};
    #pragma unroll
    for (int d = 0; d < 16; ++d) {
        float4 v = p[d];
        s4.x += v.x * v.x; s4.y += v.y * v.y; s4.z += v.z * v.z; s4.w += v.w * v.w;
    }
    sq[i] = (s4.x + s4.y) + (s4.z + s4.w);
}

// ---------------- kNN D=3: one WAVE per (b,n); register top-11 + shuffle extraction ----------------
__global__ __launch_bounds__(64) void knn3_kernel(const float* __restrict__ xt,
                                                  const float* __restrict__ sq,
                                                  int* __restrict__ idx_out) {
    const int bn = blockIdx.x;
    const int b  = bn >> 11;           // NPTS = 2048
    const int l  = threadIdx.x;

    const float qx = xt[(size_t)bn * 3 + 0];
    const float qy = xt[(size_t)bn * 3 + 1];
    const float qz = xt[(size_t)bn * 3 + 2];
    const float sqn = sq[bn];
    const float* xb  = xt + (size_t)b * NPTS * 3;
    const float* sqb_ = sq + (size_t)b * NPTS;

    unsigned long long lk[KP1];
    #pragma unroll
    for (int j = 0; j < KP1; ++j) lk[j] = ~0ULL;

    for (int m = l; m < NPTS; m += 64) {
        float dot = 0.f;
        dot += qx * xb[m * 3 + 0];
        dot += qy * xb[m * 3 + 1];
        dot += qz * xb[m * 3 + 2];
        float cd = sqn + sqb_[m] - 2.f * dot;
        unsigned long long key = dkey(cd, m);
        if (key < lk[KP1 - 1]) {
            #pragma unroll
            for (int j = 0; j < KP1; ++j) {
                bool better = key < lk[j];
                unsigned long long tk = lk[j];
                if (better) { lk[j] = key; key = tk; }
            }
        }
    }

    // width-64 min-extraction: 11 ascending unique keys == merged top-11
    #pragma unroll
    for (int k = 0; k < KP1; ++k) {
        unsigned long long mk = lk[0];
        #pragma unroll
        for (int s = 32; s >= 1; s >>= 1) {
            unsigned long long o = __shfl_xor(mk, s, 64);
            mk = (o < mk) ? o : mk;
        }
        if (k >= 1 && l == k - 1)
            idx_out[(size_t)bn * KNN + (k - 1)] = (int)(unsigned)mk;
        if (lk[0] == mk) {   // unique winner pops (static shift)
            #pragma unroll
            for (int j = 0; j < KP1 - 1; ++j) lk[j] = lk[j + 1];
            lk[KP1 - 1] = ~0ULL;
        }
    }
}

// ---------------- kNN D=64: dim-split halves + double-buffered tile (pointer-swap) ----------------
__global__ __launch_bounds__(256) void knn64_kernel(const float* __restrict__ xt,
                                                    const float* __restrict__ sq,
                                                    int* __restrict__ idx_out) {
    const int t  = threadIdx.x;
    const int qg = t >> 5;   // query slot (0..7): this lane-group's output query
    const int lc = t & 31;   // candidate lane
    const int h  = qg & 1;   // dim half within wave
    const int w  = t >> 6;   // wave id (0..3)
    const int bn0 = blockIdx.x * 8;
    const int bn  = bn0 + qg;
    const int qA  = bn0 + 2 * w;
    const int qB  = qA + 1;
    const int b   = bn >> 11;          // NPTS = 2048
    const float* xb = xt + (size_t)b * NPTS * 64;

    __shared__ __align__(16) float4 tile4[2][32][16];   // 16 KB double buffer

    float4 xqa[8], xqb[8];
    {
        const float4* pa = (const float4*)(xt + (size_t)qA * 64 + h * 32);
        const float4* pb = (const float4*)(xt + (size_t)qB * 64 + h * 32);
        #pragma unroll
        for (int i = 0; i < 8; ++i) { xqa[i] = pa[i]; xqb[i] = pb[i]; }
    }
    const float sqn = sq[bn];
    const float* sqb_ = sq + b * NPTS;

    unsigned long long lk[KP1];
    #pragma unroll
    for (int j = 0; j < KP1; ++j) lk[j] = ~0ULL;

    const int ci  = t >> 3;   // staging: candidate within tile (0..31)
    const int sub = t & 7;    // staging: 8-dim slice (2 f4 slots)

    int ro[8];
    #pragma unroll
    for (int i = 0; i < 8; ++i) ro[i] = (h * 8 + i) ^ (lc & 15);
    const int wo0 = (2 * sub)     ^ (ci & 15);
    const int wo1 = (2 * sub + 1) ^ (ci & 15);

    const float4* rb0 = &tile4[0][lc][0];
    const float4* rb1 = &tile4[1][lc][0];
    float4*       wb0 = &tile4[0][ci][0];
    float4*       wb1 = &tile4[1][ci][0];

    const float4* src = (const float4*)(xb + (size_t)ci * 64 + sub * 8);

    {
        float4 u0 = src[0], u1 = src[1];
        wb0[wo0] = u0;
        wb0[wo1] = u1;
    }
    __syncthreads();
    src += 512;

    for (int t0 = 0; t0 < NPTS; t0 += 32) {
        float4 n0, n1;
        const bool more = (t0 + 32 < NPTS);
        if (more) { n0 = src[0]; n1 = src[1]; }

        float a0 = 0.f, a1 = 0.f, a2 = 0.f, a3 = 0.f;
        float c0 = 0.f, c1 = 0.f, c2 = 0.f, c3 = 0.f;
        #pragma unroll
        for (int i = 0; i < 8; ++i) {
            float4 v = rb0[ro[i]];
            a0 += xqa[i].x * v.x; a1 += xqa[i].y * v.y;
            a2 += xqa[i].z * v.z; a3 += xqa[i].w * v.w;
            c0 += xqb[i].x * v.x; c1 += xqb[i].y * v.y;
            c2 += xqb[i].z * v.z; c3 += xqb[i].w * v.w;
        }
        float pA = (a0 + a1) + (a2 + a3);
        float pB = (c0 + c1) + (c2 + c3);
        float oA = __shfl_xor(pA, 32, 64);
        float oB = __shfl_xor(pB, 32, 64);
        float dot = (h == 0) ? (pA + oA) : (oB + pB);

        const int m = t0 + lc;
        float cd = sqn + sqb_[m] - 2.f * dot;
        unsigned long long key = dkey(cd, m);
        if (key < lk[KP1 - 1]) {
            #pragma unroll
            for (int j = 0; j < KP1; ++j) {
                bool better = key < lk[j];
                unsigned long long tk = lk[j];
                if (better) { lk[j] = key; key = tk; }
            }
        }

        if (more) {
            wb1[wo0] = n0;
            wb1[wo1] = n1;
        }
        __syncthreads();
        { const float4* tr = rb0; rb0 = rb1; rb1 = tr; }
        { float4* tw = wb0; wb0 = wb1; wb1 = tw; }
        src += 512;
    }

    #pragma unroll
    for (int k = 0; k < KP1; ++k) {
        unsigned long long mk = lk[0];
        #pragma unroll
        for (int s = 16; s >= 1; s >>= 1) {
            unsigned long long o = __shfl_xor(mk, s, 32);
            mk = (o < mk) ? o : mk;
        }
        if (k >= 1 && lc == k - 1)
            idx_out[(size_t)bn * KNN + (k - 1)] = (int)(unsigned)mk;
        if (lk[0] == mk) {
            #pragma unroll
            for (int j = 0; j < KP1 - 1; ++j) lk[j] = lk[j + 1];
            lk[KP1 - 1] = ~0ULL;
        }
    }
}

// ---------------- edge conv stage 1 v2: 8 pts/block, 2 pts/wave, 2 ch/lane ----------------
// Every LDS read serves 2 points (2 distinct addrs/wave = free 2-way). Per-channel FP
// expressions identical to verified 1-pt version -> bit-identical outputs.
__global__ __launch_bounds__(256) void edgeconv1_kernel(
    const float* __restrict__ pts, const int* __restrict__ idx,
    const float* __restrict__ w1, const float* __restrict__ s1, const float* __restrict__ b1,
    const float* __restrict__ w2, const float* __restrict__ s2, const float* __restrict__ b2,
    float* __restrict__ outt) {
    const int p0g = blockIdx.x * 8;
    const int b   = p0g >> 11;
    const int t   = threadIdx.x;
    const int p   = t >> 5;          // 0..7 (2 per wave)
    const int c32 = t & 31;
    const int pn  = p0g + p;
    const int c0 = c32, c1 = c32 + 32;

    __shared__ int   sidx[8][KNN];
    __shared__ float h1s[8][KNN][64];

    if (t < 8 * KNN) sidx[t / KNN][t % KNN] = idx[(size_t)(p0g + t / KNN) * KNN + (t % KNN)];
    __syncthreads();

    const float cx = pts[pn * 3 + 0], cy = pts[pn * 3 + 1], cz = pts[pn * 3 + 2];
    float w1r0[6], w1r1[6];
    #pragma unroll
    for (int i = 0; i < 6; ++i) { w1r0[i] = w1[c0 * 6 + i]; w1r1[i] = w1[c1 * 6 + i]; }
    const float s1c0 = s1[c0], b1c0 = b1[c0], s1c1 = s1[c1], b1c1 = b1[c1];

    #pragma unroll
    for (int k = 0; k < KNN; ++k) {
        const int m = sidx[p][k];
        const float* f = pts + ((size_t)b * NPTS + m) * 3;
        const float e0 = f[0] - cx, e1 = f[1] - cy, e2 = f[2] - cz;
        float a0 = w1r0[0] * e0 + w1r0[1] * e1 + w1r0[2] * e2
                 + w1r0[3] * cx + w1r0[4] * cy + w1r0[5] * cz;
        float a1 = w1r1[0] * e0 + w1r1[1] * e1 + w1r1[2] * e2
                 + w1r1[3] * cx + w1r1[4] * cy + w1r1[5] * cz;
        h1s[p][k][c0] = lrelu(a0 * s1c0 + b1c0);
        h1s[p][k][c1] = lrelu(a1 * s1c1 + b1c1);
    }
    __syncthreads();

    float a20[KNN], a21[KNN];
    #pragma unroll
    for (int k = 0; k < KNN; ++k) { a20[k] = 0.f; a21[k] = 0.f; }
    for (int j4 = 0; j4 < 16; ++j4) {
        float4 wv0 = *(const float4*)&w2[c0 * 64 + j4 * 4];
        float4 wv1 = *(const float4*)&w2[c1 * 64 + j4 * 4];
        #pragma unroll
        for (int k = 0; k < KNN; ++k) {
            float4 h4 = *(const float4*)&h1s[p][k][j4 * 4];
            a20[k] += wv0.x * h4.x + wv0.y * h4.y + wv0.z * h4.z + wv0.w * h4.w;
            a21[k] += wv1.x * h4.x + wv1.y * h4.y + wv1.z * h4.z + wv1.w * h4.w;
        }
    }
    const float s2c0 = s2[c0], b2c0 = b2[c0], s2c1 = s2[c1], b2c1 = b2[c1];
    float mx0 = -FLT_MAX, mx1 = -FLT_MAX;
    #pragma unroll
    for (int k = 0; k < KNN; ++k) {
        mx0 = fmaxf(mx0, lrelu(a20[k] * s2c0 + b2c0));
        mx1 = fmaxf(mx1, lrelu(a21[k] * s2c1 + b2c1));
    }
    outt[(size_t)pn * 64 + c0] = mx0;
    outt[(size_t)pn * 64 + c1] = mx1;
}

// ---------------- edge conv stage 2 v2: 8 pts/block, 2 pts/wave, 2 ch/lane ----------------
__global__ __launch_bounds__(256) void edgeconv2_kernel(
    const float* __restrict__ xin, const int* __restrict__ idx,
    const float* __restrict__ w3, const float* __restrict__ s3, const float* __restrict__ b3,
    const float* __restrict__ w4, const float* __restrict__ s4, const float* __restrict__ b4,
    float* __restrict__ outt) {
    const int p0g = blockIdx.x * 8;
    const int b   = p0g >> 11;
    const int t   = threadIdx.x;
    const int p   = t >> 5;          // 0..7
    const int c32 = t & 31;
    const int pn  = p0g + p;
    const int c0 = c32, c1 = c32 + 32;

    __shared__ int   sidx[8][KNN];
    __shared__ float cens[8][64];
    __shared__ float feas[8][KNN][64];
    __shared__ float h1s[8][KNN][64];

    if (t < 8 * KNN) sidx[t / KNN][t % KNN] = idx[(size_t)(p0g + t / KNN) * KNN + (t % KNN)];
    for (int i = t; i < 8 * 64; i += 256)
        cens[i >> 6][i & 63] = xin[((size_t)p0g + (i >> 6)) * 64 + (i & 63)];
    __syncthreads();
    for (int i = t; i < 8 * KNN * 64; i += 256) {
        int pp = i / (KNN * 64), r = i - pp * (KNN * 64);
        int k = r >> 6, c = r & 63;
        feas[pp][k][c] = xin[((size_t)b * NPTS + sidx[pp][k]) * 64 + c];
    }
    __syncthreads();

    float a0[KNN], a1[KNN];
    #pragma unroll
    for (int k = 0; k < KNN; ++k) { a0[k] = 0.f; a1[k] = 0.f; }
    float4 ab0 = {0.f, 0.f, 0.f, 0.f};
    float4 ab1 = {0.f, 0.f, 0.f, 0.f};
    for (int j4 = 0; j4 < 16; ++j4) {
        float4 wa0 = *(const float4*)&w3[c0 * 128 + j4 * 4];
        float4 wb0 = *(const float4*)&w3[c0 * 128 + 64 + j4 * 4];
        float4 wa1 = *(const float4*)&w3[c1 * 128 + j4 * 4];
        float4 wb1 = *(const float4*)&w3[c1 * 128 + 64 + j4 * 4];
        float4 c4 = *(const float4*)&cens[p][j4 * 4];
        ab0.x += (wb0.x - wa0.x) * c4.x; ab0.y += (wb0.y - wa0.y) * c4.y;
        ab0.z += (wb0.z - wa0.z) * c4.z; ab0.w += (wb0.w - wa0.w) * c4.w;
        ab1.x += (wb1.x - wa1.x) * c4.x; ab1.y += (wb1.y - wa1.y) * c4.y;
        ab1.z += (wb1.z - wa1.z) * c4.z; ab1.w += (wb1.w - wa1.w) * c4.w;
        #pragma unroll
        for (int k = 0; k < KNN; ++k) {
            float4 f4 = *(const float4*)&feas[p][k][j4 * 4];
            a0[k] += wa0.x * f4.x + wa0.y * f4.y + wa0.z * f4.z + wa0.w * f4.w;
            a1[k] += wa1.x * f4.x + wa1.y * f4.y + wa1.z * f4.z + wa1.w * f4.w;
        }
    }
    const float abase0 = (ab0.x + ab0.y) + (ab0.z + ab0.w);
    const float abase1 = (ab1.x + ab1.y) + (ab1.z + ab1.w);
    const float s3c0 = s3[c0], b3c0 = b3[c0], s3c1 = s3[c1], b3c1 = b3[c1];
    #pragma unroll
    for (int k = 0; k < KNN; ++k) {
        h1s[p][k][c0] = lrelu((a0[k] + abase0) * s3c0 + b3c0);
        h1s[p][k][c1] = lrelu((a1[k] + abase1) * s3c1 + b3c1);
    }
    __syncthreads();

    float a20[KNN], a21[KNN];
    #pragma unroll
    for (int k = 0; k < KNN; ++k) { a20[k] = 0.f; a21[k] = 0.f; }
    for (int j4 = 0; j4 < 16; ++j4) {
        float4 wv0 = *(const float4*)&w4[c0 * 64 + j4 * 4];
        float4 wv1 = *(const float4*)&w4[c1 * 64 + j4 * 4];
        #pragma unroll
        for (int k = 0; k < KNN; ++k) {
            float4 h4 = *(const float4*)&h1s[p][k][j4 * 4];
            a20[k] += wv0.x * h4.x + wv0.y * h4.y + wv0.z * h4.z + wv0.w * h4.w;
            a21[k] += wv1.x * h4.x + wv1.y * h4.y + wv1.z * h4.z + wv1.w * h4.w;
        }
    }
    const float s4c0 = s4[c0], b4c0 = b4[c0], s4c1 = s4[c1], b4c1 = b4[c1];
    float mx0 = -FLT_MAX, mx1 = -FLT_MAX;
    #pragma unroll
    for (int k = 0; k < KNN; ++k) {
        mx0 = fmaxf(mx0, lrelu(a20[k] * s4c0 + b4c0));
        mx1 = fmaxf(mx1, lrelu(a21[k] * s4c1 + b4c1));
    }
    outt[(size_t)pn * 64 + c0] = mx0;
    outt[(size_t)pn * 64 + c1] = mx1;
}

// ---------------- edge conv stage 3 v2: 8 pts/block, 2 pts/wave, 2 ch/lane ----------------
__global__ __launch_bounds__(256) void edgeconv3_kernel(
    const float* __restrict__ xin, const int* __restrict__ idx,
    const float* __restrict__ w5, const float* __restrict__ s5, const float* __restrict__ b5,
    float* __restrict__ outt) {
    const int p0g = blockIdx.x * 8;
    const int b   = p0g >> 11;
    const int t   = threadIdx.x;
    const int p   = t >> 5;
    const int c32 = t & 31;
    const int pn  = p0g + p;
    const int c0 = c32, c1 = c32 + 32;

    __shared__ int   sidx[8][KNN];
    __shared__ float cens[8][64];
    __shared__ float feas[8][KNN][64];

    if (t < 8 * KNN) sidx[t / KNN][t % KNN] = idx[(size_t)(p0g + t / KNN) * KNN + (t % KNN)];
    for (int i = t; i < 8 * 64; i += 256)
        cens[i >> 6][i & 63] = xin[((size_t)p0g + (i >> 6)) * 64 + (i & 63)];
    __syncthreads();
    for (int i = t; i < 8 * KNN * 64; i += 256) {
        int pp = i / (KNN * 64), r = i - pp * (KNN * 64);
        int k = r >> 6, c = r & 63;
        feas[pp][k][c] = xin[((size_t)b * NPTS + sidx[pp][k]) * 64 + c];
    }
    __syncthreads();

    float a0[KNN], a1[KNN];
    #pragma unroll
    for (int k = 0; k < KNN; ++k) { a0[k] = 0.f; a1[k] = 0.f; }
    float4 ab0 = {0.f, 0.f, 0.f, 0.f};
    float4 ab1 = {0.f, 0.f, 0.f, 0.f};
    for (int j4 = 0; j4 < 16; ++j4) {
        float4 wa0 = *(const float4*)&w5[c0 * 128 + j4 * 4];
        float4 wb0 = *(const float4*)&w5[c0 * 128 + 64 + j4 * 4];
        float4 wa1 = *(const float4*)&w5[c1 * 128 + j4 * 4];
        float4 wb1 = *(const float4*)&w5[c1 * 128 + 64 + j4 * 4];
        float4 c4 = *(const float4*)&cens[p][j4 * 4];
        ab0.x += (wb0.x - wa0.x) * c4.x; ab0.y += (wb0.y - wa0.y) * c4.y;
        ab0.z += (wb0.z - wa0.z) * c4.z; ab0.w += (wb0.w - wa0.w) * c4.w;
        ab1.x += (wb1.x - wa1.x) * c4.x; ab1.y += (wb1.y - wa1.y) * c4.y;
        ab1.z += (wb1.z - wa1.z) * c4.z; ab1.w += (wb1.w - wa1.w) * c4.w;
        #pragma unroll
        for (int k = 0; k < KNN; ++k) {
            float4 f4 = *(const float4*)&feas[p][k][j4 * 4];
            a0[k] += wa0.x * f4.x + wa0.y * f4.y + wa0.z * f4.z + wa0.w * f4.w;
            a1[k] += wa1.x * f4.x + wa1.y * f4.y + wa1.z * f4.z + wa1.w * f4.w;
        }
    }
    const float abase0 = (ab0.x + ab0.y) + (ab0.z + ab0.w);
    const float abase1 = (ab1.x + ab1.y) + (ab1.z + ab1.w);
    const float s5c0 = s5[c0], b5c0 = b5[c0], s5c1 = s5[c1], b5c1 = b5[c1];
    float mx0 = -FLT_MAX, mx1 = -FLT_MAX;
    #pragma unroll
    for (int k = 0; k < KNN; ++k) {
        mx0 = fmaxf(mx0, lrelu((a0[k] + abase0) * s5c0 + b5c0));
        mx1 = fmaxf(mx1, lrelu((a1[k] + abase1) * s5c1 + b5c1));
    }
    outt[(size_t)pn * 64 + c0] = mx0;
    outt[(size_t)pn * 64 + c1] = mx1;
}

// ---------------- label branch: (16) -> 64 ----------------
__global__ __launch_bounds__(64) void catvet_kernel(
    const float* __restrict__ label,
    const float* __restrict__ w7, const float* __restrict__ s7, const float* __restrict__ b7,
    float* __restrict__ catv) {
    const int b = blockIdx.x, c = threadIdx.x;
    float a = 0.f;
    #pragma unroll
    for (int i = 0; i < 16; ++i) a += w7[c * 16 + i] * label[b * 16 + i];
    catv[b * 64 + c] = lrelu(a * s7[c] + b7[c]);
}

// ---------------- w6 transpose: w6t[k][c] = w6[c][k] (one-time, 768 KB) ----------------
__global__ void w6t_kernel(const float* __restrict__ w6, float* __restrict__ w6t) {
    int i = blockIdx.x * 256 + threadIdx.x;
    if (i >= 192 * 1024) return;
    int k = i >> 10, c = i & 1023;
    w6t[i] = w6[c * 192 + k];
}

// ---------------- global feature GEMM: raw max_n( w6 . x[n] ) per channel ----------------
constexpr int OPTS = 32;
__global__ __launch_bounds__(256) void out4max_kernel(
    const float* __restrict__ out1t, const float* __restrict__ out2t, const float* __restrict__ out3t,
    const float* __restrict__ w6t, float* __restrict__ partial) {
    const int blk = blockIdx.x;
    const int b   = blk >> 6;
    const int nt  = blk & 63;
    const int t   = threadIdx.x;

    __shared__ float xs[192 * OPTS];
    for (int idx = t; idx < 192 * OPTS; idx += 256) {
        int p = idx / 192, r = idx - p * 192;
        const size_t gp = (size_t)b * NPTS + nt * OPTS + p;
        float val;
        if (r < 64)       val = out1t[gp * 64 + r];
        else if (r < 128) val = out2t[gp * 64 + (r - 64)];
        else              val = out3t[gp * 64 + (r - 128)];
        xs[r * OPTS + p] = val;
    }
    __syncthreads();

    float mx0 = -FLT_MAX, mx1 = -FLT_MAX, mx2 = -FLT_MAX, mx3 = -FLT_MAX;
    #pragma unroll
    for (int pg = 0; pg < OPTS / 16; ++pg) {
        float acc0[16], acc1[16], acc2[16], acc3[16];
        #pragma unroll
        for (int p = 0; p < 16; ++p) { acc0[p] = 0.f; acc1[p] = 0.f; acc2[p] = 0.f; acc3[p] = 0.f; }
        #pragma unroll 2
        for (int k = 0; k < 192; ++k) {
            float4 wv = *(const float4*)&w6t[(size_t)k * 1024 + t * 4];
            const float4* xr4 = (const float4*)&xs[k * OPTS + pg * 16];
            #pragma unroll
            for (int p4 = 0; p4 < 4; ++p4) {
                float4 xv = xr4[p4];
                acc0[p4 * 4 + 0] += wv.x * xv.x; acc0[p4 * 4 + 1] += wv.x * xv.y;
                acc0[p4 * 4 + 2] += wv.x * xv.z; acc0[p4 * 4 + 3] += wv.x * xv.w;
                acc1[p4 * 4 + 0] += wv.y * xv.x; acc1[p4 * 4 + 1] += wv.y * xv.y;
                acc1[p4 * 4 + 2] += wv.y * xv.z; acc1[p4 * 4 + 3] += wv.y * xv.w;
                acc2[p4 * 4 + 0] += wv.z * xv.x; acc2[p4 * 4 + 1] += wv.z * xv.y;
                acc2[p4 * 4 + 2] += wv.z * xv.z; acc2[p4 * 4 + 3] += wv.z * xv.w;
                acc3[p4 * 4 + 0] += wv.w * xv.x; acc3[p4 * 4 + 1] += wv.w * xv.y;
                acc3[p4 * 4 + 2] += wv.w * xv.z; acc3[p4 * 4 + 3] += wv.w * xv.w;
            }
        }
        #pragma unroll
        for (int p = 0; p < 16; ++p) {
            mx0 = fmaxf(mx0, acc0[p]); mx1 = fmaxf(mx1, acc1[p]);
            mx2 = fmaxf(mx2, acc2[p]); mx3 = fmaxf(mx3, acc3[p]);
        }
    }
    float4 o = {mx0, mx1, mx2, mx3};
    *(float4*)&partial[(size_t)blk * 1024 + t * 4] = o;
}

__global__ __launch_bounds__(256) void out4reduce_kernel(
    const float* __restrict__ partial,
    const float* __restrict__ s6, const float* __restrict__ b6,
    float* __restrict__ out4m) {
    const int i = blockIdx.x * 256 + threadIdx.x;
    const int b = i >> 10, c = i & 1023;
    float m = -FLT_MAX;
    for (int nt = 0; nt < 64; ++nt)
        m = fmaxf(m, partial[((size_t)b * 64 + nt) * 1024 + c]);
    out4m[i] = lrelu(m * s6[c] + b6[c]);
}

// ---------------- per-batch head bias: g[b][o] = wp1[o,192:1280] . [out4m;catv] ----------------
__global__ __launch_bounds__(256) void gbias_kernel(
    const float* __restrict__ out4m, const float* __restrict__ catv,
    const float* __restrict__ wp1, float* __restrict__ g) {
    const int b = blockIdx.x, t = threadIdx.x;
    __shared__ float v[1088];
    for (int i = t; i < 1088; i += 256)
        v[i] = (i < 1024) ? out4m[(size_t)b * 1024 + i] : catv[(size_t)b * 64 + (i - 1024)];
    __syncthreads();
    const float* w = wp1 + (size_t)t * 1280 + 192;
    float4 s4 = {0.f, 0.f, 0.f, 0.f};
    for (int i = 0; i < 272; ++i) {
        float4 wv = *(const float4*)&w[i * 4];
        float4 vv = *(const float4*)&v[i * 4];
        s4.x += wv.x * vv.x; s4.y += wv.y * vv.y; s4.z += wv.z * vv.z; s4.w += wv.w * vv.w;
    }
    g[(size_t)b * 256 + t] = (s4.x + s4.y) + (s4.z + s4.w);
}

// ---------------- per-point head (tiled GEMM): 192 -> 256 -> 256 -> 128 -> 6 ----------------
constexpr int HP = 16;
constexpr int KC = 16;

__global__ __launch_bounds__(256) void head_kernel(
    const float* __restrict__ out1t, const float* __restrict__ out2t, const float* __restrict__ out3t,
    const float* __restrict__ g,
    const float* __restrict__ wp1, const float* __restrict__ sp1, const float* __restrict__ bp1,
    const float* __restrict__ wp2, const float* __restrict__ sp2, const float* __restrict__ bp2,
    const float* __restrict__ wp3, const float* __restrict__ sp3, const float* __restrict__ bp3,
    const float* __restrict__ wp4, float* __restrict__ out) {
    const int p0 = blockIdx.x * HP;
    const int b  = p0 >> 11;
    const int t  = threadIdx.x;

    __shared__ float smA[4096];
    __shared__ float smB[4096];
    __shared__ float smW[KC * 256];

    for (int e = t; e < 192 * HP; e += 256) {
        int p = e / 192, k = e - p * 192;
        float val;
        if (k < 64)       val = out1t[((size_t)(p0 + p)) * 64 + k];
        else if (k < 128) val = out2t[((size_t)(p0 + p)) * 64 + (k - 64)];
        else              val = out3t[((size_t)(p0 + p)) * 64 + (k - 128)];
        smA[k * HP + p] = val;
    }

    const int og = t & 31;
    const int pg = t >> 5;

    float acc[2][8];
    #pragma unroll
    for (int i = 0; i < 8; ++i) {
        float gv = g[(size_t)b * 256 + og * 8 + i];
        acc[0][i] = gv; acc[1][i] = gv;
    }
    for (int kc = 0; kc < 192 / KC; ++kc) {
        __syncthreads();
        #pragma unroll
        for (int it = 0; it < KC; ++it)
            smW[it * 256 + t] = wp1[(size_t)t * 1280 + kc * KC + it];
        __syncthreads();
        #pragma unroll 4
        for (int kk = 0; kk < KC; ++kk) {
            int k = kc * KC + kk;
            float2 xv = *(const float2*)&smA[k * HP + pg * 2];
            float4 w0 = *(const float4*)&smW[kk * 256 + og * 8];
            float4 w1v = *(const float4*)&smW[kk * 256 + og * 8 + 4];
            float wv[8] = {w0.x, w0.y, w0.z, w0.w, w1v.x, w1v.y, w1v.z, w1v.w};
            #pragma unroll
            for (int i = 0; i < 8; ++i) {
                acc[0][i] += xv.x * wv[i];
                acc[1][i] += xv.y * wv[i];
            }
        }
    }
    #pragma unroll
    for (int i = 0; i < 8; ++i) {
        int o = og * 8 + i;
        float sc = sp1[o], bc = bp1[o];
        smB[o * HP + pg * 2 + 0] = lrelu(acc[0][i] * sc + bc);
        smB[o * HP + pg * 2 + 1] = lrelu(acc[1][i] * sc + bc);
    }

    float acc2[2][8];
    #pragma unroll
    for (int i = 0; i < 8; ++i) { acc2[0][i] = 0.f; acc2[1][i] = 0.f; }
    for (int kc = 0; kc < 256 / KC; ++kc) {
        __syncthreads();
        #pragma unroll
        for (int it = 0; it < KC; ++it)
            smW[it * 256 + t] = wp2[(size_t)t * 256 + kc * KC + it];
        __syncthreads();
        #pragma unroll 4
        for (int kk = 0; kk < KC; ++kk) {
            int k = kc * KC + kk;
            float2 xv = *(const float2*)&smB[k * HP + pg * 2];
            float4 w0 = *(const float4*)&smW[kk * 256 + og * 8];
            float4 w1v = *(const float4*)&smW[kk * 256 + og * 8 + 4];
            float wv[8] = {w0.x, w0.y, w0.z, w0.w, w1v.x, w1v.y, w1v.z, w1v.w};
            #pragma unroll
            for (int i = 0; i < 8; ++i) {
                acc2[0][i] += xv.x * wv[i];
                acc2[1][i] += xv.y * wv[i];
            }
        }
    }
    __syncthreads();
    #pragma unroll
    for (int i = 0; i < 8; ++i) {
        int o = og * 8 + i;
        float sc = sp2[o], bc = bp2[o];
        smA[o * HP + pg * 2 + 0] = lrelu(acc2[0][i] * sc + bc);
        smA[o * HP + pg * 2 + 1] = lrelu(acc2[1][i] * sc + bc);
    }

    const int og3 = t & 15;
    const int p3  = t >> 4;
    float acc3[8];
    #pragma unroll
    for (int i = 0; i < 8; ++i) acc3[i] = 0.f;
    for (int kc = 0; kc < 256 / KC; ++kc) {
        __syncthreads();
        for (int e = t; e < KC * 128; e += 256) {
            int kk = e >> 7, o = e & 127;
            smW[kk * 128 + o] = wp3[(size_t)o * 256 + kc * KC + kk];
        }
        __syncthreads();
        #pragma unroll 4
        for (int kk = 0; kk < KC; ++kk) {
            int k = kc * KC + kk;
            float xv = smA[k * HP + p3];
            float4 w0 = *(const float4*)&smW[kk * 128 + og3 * 8];
            float4 w1v = *(const float4*)&smW[kk * 128 + og3 * 8 + 4];
            float wv[8] = {w0.x, w0.y, w0.z, w0.w, w1v.x, w1v.y, w1v.z, w1v.w};
            #pragma unroll
            for (int i = 0; i < 8; ++i) acc3[i] += xv * wv[i];
        }
    }
    __syncthreads();
    #pragma unroll
    for (int i = 0; i < 8; ++i) {
        int o = og3 * 8 + i;
        float sc = sp3[o], bc = bp3[o];
        smB[o * HP + p3] = lrelu(acc3[i] * sc + bc);
    }
    __syncthreads();

    if (t < HP * 6) {
        int p = t / 6, o = t - p * 6;
        float4 s4 = {0.f, 0.f, 0.f, 0.f};
        for (int k4 = 0; k4 < 32; ++k4) {
            float4 wv = *(const float4*)&wp4[o * 128 + k4 * 4];
            s4.x += wv.x * smB[(k4 * 4 + 0) * HP + p];
            s4.y += wv.y * smB[(k4 * 4 + 1) * HP + p];
            s4.z += wv.z * smB[(k4 * 4 + 2) * HP + p];
            s4.w += wv.w * smB[(k4 * 4 + 3) * HP + p];
        }
        out[((size_t)(p0 + p)) * 6 + o] = (s4.x + s4.y) + (s4.z + s4.w);
    }
}

extern "C" void kernel_launch(void* const* d_in, const int* in_sizes, int n_in,
                              void* d_out, int out_size, void* d_ws, size_t ws_size,
                              hipStream_t stream) {
    const float* points = (const float*)d_in[0];
    const float* label  = (const float*)d_in[1];
    const float* w1  = (const float*)d_in[2];
    const float* s1  = (const float*)d_in[3];
    const float* b1  = (const float*)d_in[4];
    const float* w2  = (const float*)d_in[5];
    const float* s2  = (const float*)d_in[6];
    const float* b2  = (const float*)d_in[7];
    const float* w3  = (const float*)d_in[8];
    const float* s3  = (const float*)d_in[9];
    const float* b3  = (const float*)d_in[10];
    const float* w4  = (const float*)d_in[11];
    const float* s4  = (const float*)d_in[12];
    const float* b4  = (const float*)d_in[13];
    const float* w5  = (const float*)d_in[14];
    const float* s5  = (const float*)d_in[15];
    const float* b5  = (const float*)d_in[16];
    const float* w6  = (const float*)d_in[17];
    const float* s6  = (const float*)d_in[18];
    const float* b6  = (const float*)d_in[19];
    const float* w7  = (const float*)d_in[20];
    const float* s7  = (const float*)d_in[21];
    const float* b7  = (const float*)d_in[22];
    const float* wp1 = (const float*)d_in[23];
    const float* sp1 = (const float*)d_in[24];
    const float* bp1 = (const float*)d_in[25];
    const float* wp2 = (const float*)d_in[26];
    const float* sp2 = (const float*)d_in[27];
    const float* bp2 = (const float*)d_in[28];
    const float* wp3 = (const float*)d_in[29];
    const float* sp3 = (const float*)d_in[30];
    const float* bp3 = (const float*)d_in[31];
    const float* wp4 = (const float*)d_in[32];

    float* ws = (float*)d_ws;
    size_t off = 0;
    auto alloc = [&](size_t nf) { float* p = ws + off; off += nf; return p; };
    float* out1t = alloc((size_t)BATCH * NPTS * 64);
    float* out2t = alloc((size_t)BATCH * NPTS * 64);
    float* out3t = alloc((size_t)BATCH * NPTS * 64);
    float* sqb   = alloc((size_t)BATCH * NPTS);
    float* out4m = alloc((size_t)BATCH * 1024);
    float* catv  = alloc((size_t)BATCH * 64);
    float* gb    = alloc((size_t)BATCH * 256);
    float* w6t   = alloc((size_t)192 * 1024);
    float* part  = alloc((size_t)512 * 1024);
    int* idx1 = (int*)alloc((size_t)BATCH * NPTS * KNN);
    int* idx2 = (int*)alloc((size_t)BATCH * NPTS * KNN);
    int* idx3 = (int*)alloc((size_t)BATCH * NPTS * KNN);

    const int BN = BATCH * NPTS;
    const int sqBlocks = (BN + 255) / 256;

    // stage 1
    sq_kernel<3><<<sqBlocks, 256, 0, stream>>>(points, sqb);
    knn3_kernel<<<BN, 64, 0, stream>>>(points, sqb, idx1);
    edgeconv1_kernel<<<BN / 8, 256, 0, stream>>>(points, idx1, w1, s1, b1, w2, s2, b2, out1t);

    // stage 2
    sq64_kernel<<<sqBlocks, 256, 0, stream>>>(out1t, sqb);
    knn64_kernel<<<BN / 8, 256, 0, stream>>>(out1t, sqb, idx2);
    edgeconv2_kernel<<<BN / 8, 256, 0, stream>>>(out1t, idx2, w3, s3, b3, w4, s4, b4, out2t);

    // stage 3
    sq64_kernel<<<sqBlocks, 256, 0, stream>>>(out2t, sqb);
    knn64_kernel<<<BN / 8, 256, 0, stream>>>(out2t, sqb, idx3);
    edgeconv3_kernel<<<BN / 8, 256, 0, stream>>>(out2t, idx3, w5, s5, b5, out3t);

    // global branches
    catvet_kernel<<<BATCH, 64, 0, stream>>>(label, w7, s7, b7, catv);
    w6t_kernel<<<(192 * 1024 + 255) / 256, 256, 0, stream>>>(w6, w6t);
    out4max_kernel<<<512, 256, 0, stream>>>(out1t, out2t, out3t, w6t, part);
    out4reduce_kernel<<<BATCH * 1024 / 256, 256, 0, stream>>>(part, s6, b6, out4m);
    gbias_kernel<<<BATCH, 256, 0, stream>>>(out4m, catv, wp1, gb);

    // head
    head_kernel<<<BN / HP, 256, 0, stream>>>(out1t, out2t, out3t, gb,
                                             wp1, sp1, bp1, wp2, sp2, bp2, wp3, sp3, bp3,
                                             wp4, (float*)d_out);
}

// Round 12
// 974.077 us; speedup vs baseline: 1.1285x; 1.1285x over previous
//
#include <hip/hip_runtime.h>
#include <float.h>

#define NEG 0.2f
constexpr int BATCH = 8;
constexpr int NPTS  = 2048;
constexpr int KNN   = 10;
constexpr int KP1   = 11;

__device__ __forceinline__ float lrelu(float x) { return x > 0.f ? x : NEG * x; }

// ordered-u64 key: (monotone uint of d2) << 32 | idx  => u64 '<' == (d2 asc, idx asc)
__device__ __forceinline__ unsigned long long dkey(float d, int m) {
    unsigned u = __float_as_uint(d);
    u ^= (unsigned)((int)u >> 31) | 0x80000000u;
    return ((unsigned long long)u << 32) | (unsigned)m;
}

// ---------------- squared-norm per point ----------------
template<int D>
__global__ void sq_kernel(const float* __restrict__ xt, float* __restrict__ sq) {
    int i = blockIdx.x * 256 + threadIdx.x;
    if (i >= BATCH * NPTS) return;
    const float* p = xt + (size_t)i * D;
    float s = 0.f;
    #pragma unroll
    for (int d = 0; d < D; ++d) s += p[d] * p[d];
    sq[i] = s;
}

__global__ void sq64_kernel(const float* __restrict__ xt, float* __restrict__ sq) {
    int i = blockIdx.x * 256 + threadIdx.x;
    if (i >= BATCH * NPTS) return;
    const float4* p = (const float4*)(xt + (size_t)i * 64);
    float4 s4 = {0.f, 0.f, 0.f, 0.f};
    #pragma unroll
    for (int d = 0; d < 16; ++d) {
        float4 v = p[d];
        s4.x += v.x * v.x; s4.y += v.y * v.y; s4.z += v.z * v.z; s4.w += v.w * v.w;
    }
    sq[i] = (s4.x + s4.y) + (s4.z + s4.w);
}

// ---------------- kNN D=3: one WAVE per (b,n); register top-11 + shuffle extraction ----------------
__global__ __launch_bounds__(64) void knn3_kernel(const float* __restrict__ xt,
                                                  const float* __restrict__ sq,
                                                  int* __restrict__ idx_out) {
    const int bn = blockIdx.x;
    const int b  = bn >> 11;           // NPTS = 2048
    const int l  = threadIdx.x;

    const float qx = xt[(size_t)bn * 3 + 0];
    const float qy = xt[(size_t)bn * 3 + 1];
    const float qz = xt[(size_t)bn * 3 + 2];
    const float sqn = sq[bn];
    const float* xb  = xt + (size_t)b * NPTS * 3;
    const float* sqb_ = sq + (size_t)b * NPTS;

    unsigned long long lk[KP1];
    #pragma unroll
    for (int j = 0; j < KP1; ++j) lk[j] = ~0ULL;

    for (int m = l; m < NPTS; m += 64) {
        float dot = 0.f;
        dot += qx * xb[m * 3 + 0];
        dot += qy * xb[m * 3 + 1];
        dot += qz * xb[m * 3 + 2];
        float cd = sqn + sqb_[m] - 2.f * dot;
        unsigned long long key = dkey(cd, m);
        if (key < lk[KP1 - 1]) {
            #pragma unroll
            for (int j = 0; j < KP1; ++j) {
                bool better = key < lk[j];
                unsigned long long tk = lk[j];
                if (better) { lk[j] = key; key = tk; }
            }
        }
    }

    #pragma unroll
    for (int k = 0; k < KP1; ++k) {
        unsigned long long mk = lk[0];
        #pragma unroll
        for (int s = 32; s >= 1; s >>= 1) {
            unsigned long long o = __shfl_xor(mk, s, 64);
            mk = (o < mk) ? o : mk;
        }
        if (k >= 1 && l == k - 1)
            idx_out[(size_t)bn * KNN + (k - 1)] = (int)(unsigned)mk;
        if (lk[0] == mk) {
            #pragma unroll
            for (int j = 0; j < KP1 - 1; ++j) lk[j] = lk[j + 1];
            lk[KP1 - 1] = ~0ULL;
        }
    }
}

// ---------------- kNN D=64: dim-split halves + double-buffered tile (pointer-swap) ----------------
__global__ __launch_bounds__(256) void knn64_kernel(const float* __restrict__ xt,
                                                    const float* __restrict__ sq,
                                                    int* __restrict__ idx_out) {
    const int t  = threadIdx.x;
    const int qg = t >> 5;
    const int lc = t & 31;
    const int h  = qg & 1;
    const int w  = t >> 6;
    const int bn0 = blockIdx.x * 8;
    const int bn  = bn0 + qg;
    const int qA  = bn0 + 2 * w;
    const int qB  = qA + 1;
    const int b   = bn >> 11;
    const float* xb = xt + (size_t)b * NPTS * 64;

    __shared__ __align__(16) float4 tile4[2][32][16];

    float4 xqa[8], xqb[8];
    {
        const float4* pa = (const float4*)(xt + (size_t)qA * 64 + h * 32);
        const float4* pb = (const float4*)(xt + (size_t)qB * 64 + h * 32);
        #pragma unroll
        for (int i = 0; i < 8; ++i) { xqa[i] = pa[i]; xqb[i] = pb[i]; }
    }
    const float sqn = sq[bn];
    const float* sqb_ = sq + b * NPTS;

    unsigned long long lk[KP1];
    #pragma unroll
    for (int j = 0; j < KP1; ++j) lk[j] = ~0ULL;

    const int ci  = t >> 3;
    const int sub = t & 7;

    int ro[8];
    #pragma unroll
    for (int i = 0; i < 8; ++i) ro[i] = (h * 8 + i) ^ (lc & 15);
    const int wo0 = (2 * sub)     ^ (ci & 15);
    const int wo1 = (2 * sub + 1) ^ (ci & 15);

    const float4* rb0 = &tile4[0][lc][0];
    const float4* rb1 = &tile4[1][lc][0];
    float4*       wb0 = &tile4[0][ci][0];
    float4*       wb1 = &tile4[1][ci][0];

    const float4* src = (const float4*)(xb + (size_t)ci * 64 + sub * 8);

    {
        float4 u0 = src[0], u1 = src[1];
        wb0[wo0] = u0;
        wb0[wo1] = u1;
    }
    __syncthreads();
    src += 512;

    for (int t0 = 0; t0 < NPTS; t0 += 32) {
        float4 n0, n1;
        const bool more = (t0 + 32 < NPTS);
        if (more) { n0 = src[0]; n1 = src[1]; }

        float a0 = 0.f, a1 = 0.f, a2 = 0.f, a3 = 0.f;
        float c0 = 0.f, c1 = 0.f, c2 = 0.f, c3 = 0.f;
        #pragma unroll
        for (int i = 0; i < 8; ++i) {
            float4 v = rb0[ro[i]];
            a0 += xqa[i].x * v.x; a1 += xqa[i].y * v.y;
            a2 += xqa[i].z * v.z; a3 += xqa[i].w * v.w;
            c0 += xqb[i].x * v.x; c1 += xqb[i].y * v.y;
            c2 += xqb[i].z * v.z; c3 += xqb[i].w * v.w;
        }
        float pA = (a0 + a1) + (a2 + a3);
        float pB = (c0 + c1) + (c2 + c3);
        float oA = __shfl_xor(pA, 32, 64);
        float oB = __shfl_xor(pB, 32, 64);
        float dot = (h == 0) ? (pA + oA) : (oB + pB);

        const int m = t0 + lc;
        float cd = sqn + sqb_[m] - 2.f * dot;
        unsigned long long key = dkey(cd, m);
        if (key < lk[KP1 - 1]) {
            #pragma unroll
            for (int j = 0; j < KP1; ++j) {
                bool better = key < lk[j];
                unsigned long long tk = lk[j];
                if (better) { lk[j] = key; key = tk; }
            }
        }

        if (more) {
            wb1[wo0] = n0;
            wb1[wo1] = n1;
        }
        __syncthreads();
        { const float4* tr = rb0; rb0 = rb1; rb1 = tr; }
        { float4* tw = wb0; wb0 = wb1; wb1 = tw; }
        src += 512;
    }

    #pragma unroll
    for (int k = 0; k < KP1; ++k) {
        unsigned long long mk = lk[0];
        #pragma unroll
        for (int s = 16; s >= 1; s >>= 1) {
            unsigned long long o = __shfl_xor(mk, s, 32);
            mk = (o < mk) ? o : mk;
        }
        if (k >= 1 && lc == k - 1)
            idx_out[(size_t)bn * KNN + (k - 1)] = (int)(unsigned)mk;
        if (lk[0] == mk) {
            #pragma unroll
            for (int j = 0; j < KP1 - 1; ++j) lk[j] = lk[j + 1];
            lk[KP1 - 1] = ~0ULL;
        }
    }
}

// ---------------- edge conv stage 1 v2: 8 pts/block, 2 pts/wave, 2 ch/lane ----------------
__global__ __launch_bounds__(256) void edgeconv1_kernel(
    const float* __restrict__ pts, const int* __restrict__ idx,
    const float* __restrict__ w1, const float* __restrict__ s1, const float* __restrict__ b1,
    const float* __restrict__ w2, const float* __restrict__ s2, const float* __restrict__ b2,
    float* __restrict__ outt) {
    const int p0g = blockIdx.x * 8;
    const int b   = p0g >> 11;
    const int t   = threadIdx.x;
    const int p   = t >> 5;
    const int c32 = t & 31;
    const int pn  = p0g + p;
    const int c0 = c32, c1 = c32 + 32;

    __shared__ int   sidx[8][KNN];
    __shared__ float h1s[8][KNN][64];

    if (t < 8 * KNN) sidx[t / KNN][t % KNN] = idx[(size_t)(p0g + t / KNN) * KNN + (t % KNN)];
    __syncthreads();

    const float cx = pts[pn * 3 + 0], cy = pts[pn * 3 + 1], cz = pts[pn * 3 + 2];
    float w1r0[6], w1r1[6];
    #pragma unroll
    for (int i = 0; i < 6; ++i) { w1r0[i] = w1[c0 * 6 + i]; w1r1[i] = w1[c1 * 6 + i]; }
    const float s1c0 = s1[c0], b1c0 = b1[c0], s1c1 = s1[c1], b1c1 = b1[c1];

    #pragma unroll
    for (int k = 0; k < KNN; ++k) {
        const int m = sidx[p][k];
        const float* f = pts + ((size_t)b * NPTS + m) * 3;
        const float e0 = f[0] - cx, e1 = f[1] - cy, e2 = f[2] - cz;
        float a0 = w1r0[0] * e0 + w1r0[1] * e1 + w1r0[2] * e2
                 + w1r0[3] * cx + w1r0[4] * cy + w1r0[5] * cz;
        float a1 = w1r1[0] * e0 + w1r1[1] * e1 + w1r1[2] * e2
                 + w1r1[3] * cx + w1r1[4] * cy + w1r1[5] * cz;
        h1s[p][k][c0] = lrelu(a0 * s1c0 + b1c0);
        h1s[p][k][c1] = lrelu(a1 * s1c1 + b1c1);
    }
    __syncthreads();

    float a20[KNN], a21[KNN];
    #pragma unroll
    for (int k = 0; k < KNN; ++k) { a20[k] = 0.f; a21[k] = 0.f; }
    for (int j4 = 0; j4 < 16; ++j4) {
        float4 wv0 = *(const float4*)&w2[c0 * 64 + j4 * 4];
        float4 wv1 = *(const float4*)&w2[c1 * 64 + j4 * 4];
        #pragma unroll
        for (int k = 0; k < KNN; ++k) {
            float4 h4 = *(const float4*)&h1s[p][k][j4 * 4];
            a20[k] += wv0.x * h4.x + wv0.y * h4.y + wv0.z * h4.z + wv0.w * h4.w;
            a21[k] += wv1.x * h4.x + wv1.y * h4.y + wv1.z * h4.z + wv1.w * h4.w;
        }
    }
    const float s2c0 = s2[c0], b2c0 = b2[c0], s2c1 = s2[c1], b2c1 = b2[c1];
    float mx0 = -FLT_MAX, mx1 = -FLT_MAX;
    #pragma unroll
    for (int k = 0; k < KNN; ++k) {
        mx0 = fmaxf(mx0, lrelu(a20[k] * s2c0 + b2c0));
        mx1 = fmaxf(mx1, lrelu(a21[k] * s2c1 + b2c1));
    }
    outt[(size_t)pn * 64 + c0] = mx0;
    outt[(size_t)pn * 64 + c1] = mx1;
}

// ---------------- edge conv stage 2 v2: 8 pts/block, 2 pts/wave, 2 ch/lane ----------------
__global__ __launch_bounds__(256) void edgeconv2_kernel(
    const float* __restrict__ xin, const int* __restrict__ idx,
    const float* __restrict__ w3, const float* __restrict__ s3, const float* __restrict__ b3,
    const float* __restrict__ w4, const float* __restrict__ s4, const float* __restrict__ b4,
    float* __restrict__ outt) {
    const int p0g = blockIdx.x * 8;
    const int b   = p0g >> 11;
    const int t   = threadIdx.x;
    const int p   = t >> 5;
    const int c32 = t & 31;
    const int pn  = p0g + p;
    const int c0 = c32, c1 = c32 + 32;

    __shared__ int   sidx[8][KNN];
    __shared__ float cens[8][64];
    __shared__ float feas[8][KNN][64];
    __shared__ float h1s[8][KNN][64];

    if (t < 8 * KNN) sidx[t / KNN][t % KNN] = idx[(size_t)(p0g + t / KNN) * KNN + (t % KNN)];
    for (int i = t; i < 8 * 64; i += 256)
        cens[i >> 6][i & 63] = xin[((size_t)p0g + (i >> 6)) * 64 + (i & 63)];
    __syncthreads();
    for (int i = t; i < 8 * KNN * 64; i += 256) {
        int pp = i / (KNN * 64), r = i - pp * (KNN * 64);
        int k = r >> 6, c = r & 63;
        feas[pp][k][c] = xin[((size_t)b * NPTS + sidx[pp][k]) * 64 + c];
    }
    __syncthreads();

    float a0[KNN], a1[KNN];
    #pragma unroll
    for (int k = 0; k < KNN; ++k) { a0[k] = 0.f; a1[k] = 0.f; }
    float4 ab0 = {0.f, 0.f, 0.f, 0.f};
    float4 ab1 = {0.f, 0.f, 0.f, 0.f};
    for (int j4 = 0; j4 < 16; ++j4) {
        float4 wa0 = *(const float4*)&w3[c0 * 128 + j4 * 4];
        float4 wb0 = *(const float4*)&w3[c0 * 128 + 64 + j4 * 4];
        float4 wa1 = *(const float4*)&w3[c1 * 128 + j4 * 4];
        float4 wb1 = *(const float4*)&w3[c1 * 128 + 64 + j4 * 4];
        float4 c4 = *(const float4*)&cens[p][j4 * 4];
        ab0.x += (wb0.x - wa0.x) * c4.x; ab0.y += (wb0.y - wa0.y) * c4.y;
        ab0.z += (wb0.z - wa0.z) * c4.z; ab0.w += (wb0.w - wa0.w) * c4.w;
        ab1.x += (wb1.x - wa1.x) * c4.x; ab1.y += (wb1.y - wa1.y) * c4.y;
        ab1.z += (wb1.z - wa1.z) * c4.z; ab1.w += (wb1.w - wa1.w) * c4.w;
        #pragma unroll
        for (int k = 0; k < KNN; ++k) {
            float4 f4 = *(const float4*)&feas[p][k][j4 * 4];
            a0[k] += wa0.x * f4.x + wa0.y * f4.y + wa0.z * f4.z + wa0.w * f4.w;
            a1[k] += wa1.x * f4.x + wa1.y * f4.y + wa1.z * f4.z + wa1.w * f4.w;
        }
    }
    const float abase0 = (ab0.x + ab0.y) + (ab0.z + ab0.w);
    const float abase1 = (ab1.x + ab1.y) + (ab1.z + ab1.w);
    const float s3c0 = s3[c0], b3c0 = b3[c0], s3c1 = s3[c1], b3c1 = b3[c1];
    #pragma unroll
    for (int k = 0; k < KNN; ++k) {
        h1s[p][k][c0] = lrelu((a0[k] + abase0) * s3c0 + b3c0);
        h1s[p][k][c1] = lrelu((a1[k] + abase1) * s3c1 + b3c1);
    }
    __syncthreads();

    float a20[KNN], a21[KNN];
    #pragma unroll
    for (int k = 0; k < KNN; ++k) { a20[k] = 0.f; a21[k] = 0.f; }
    for (int j4 = 0; j4 < 16; ++j4) {
        float4 wv0 = *(const float4*)&w4[c0 * 64 + j4 * 4];
        float4 wv1 = *(const float4*)&w4[c1 * 64 + j4 * 4];
        #pragma unroll
        for (int k = 0; k < KNN; ++k) {
            float4 h4 = *(const float4*)&h1s[p][k][j4 * 4];
            a20[k] += wv0.x * h4.x + wv0.y * h4.y + wv0.z * h4.z + wv0.w * h4.w;
            a21[k] += wv1.x * h4.x + wv1.y * h4.y + wv1.z * h4.z + wv1.w * h4.w;
        }
    }
    const float s4c0 = s4[c0], b4c0 = b4[c0], s4c1 = s4[c1], b4c1 = b4[c1];
    float mx0 = -FLT_MAX, mx1 = -FLT_MAX;
    #pragma unroll
    for (int k = 0; k < KNN; ++k) {
        mx0 = fmaxf(mx0, lrelu(a20[k] * s4c0 + b4c0));
        mx1 = fmaxf(mx1, lrelu(a21[k] * s4c1 + b4c1));
    }
    outt[(size_t)pn * 64 + c0] = mx0;
    outt[(size_t)pn * 64 + c1] = mx1;
}

// ---------------- edge conv stage 3 v2: 8 pts/block, 2 pts/wave, 2 ch/lane ----------------
__global__ __launch_bounds__(256) void edgeconv3_kernel(
    const float* __restrict__ xin, const int* __restrict__ idx,
    const float* __restrict__ w5, const float* __restrict__ s5, const float* __restrict__ b5,
    float* __restrict__ outt) {
    const int p0g = blockIdx.x * 8;
    const int b   = p0g >> 11;
    const int t   = threadIdx.x;
    const int p   = t >> 5;
    const int c32 = t & 31;
    const int pn  = p0g + p;
    const int c0 = c32, c1 = c32 + 32;

    __shared__ int   sidx[8][KNN];
    __shared__ float cens[8][64];
    __shared__ float feas[8][KNN][64];

    if (t < 8 * KNN) sidx[t / KNN][t % KNN] = idx[(size_t)(p0g + t / KNN) * KNN + (t % KNN)];
    for (int i = t; i < 8 * 64; i += 256)
        cens[i >> 6][i & 63] = xin[((size_t)p0g + (i >> 6)) * 64 + (i & 63)];
    __syncthreads();
    for (int i = t; i < 8 * KNN * 64; i += 256) {
        int pp = i / (KNN * 64), r = i - pp * (KNN * 64);
        int k = r >> 6, c = r & 63;
        feas[pp][k][c] = xin[((size_t)b * NPTS + sidx[pp][k]) * 64 + c];
    }
    __syncthreads();

    float a0[KNN], a1[KNN];
    #pragma unroll
    for (int k = 0; k < KNN; ++k) { a0[k] = 0.f; a1[k] = 0.f; }
    float4 ab0 = {0.f, 0.f, 0.f, 0.f};
    float4 ab1 = {0.f, 0.f, 0.f, 0.f};
    for (int j4 = 0; j4 < 16; ++j4) {
        float4 wa0 = *(const float4*)&w5[c0 * 128 + j4 * 4];
        float4 wb0 = *(const float4*)&w5[c0 * 128 + 64 + j4 * 4];
        float4 wa1 = *(const float4*)&w5[c1 * 128 + j4 * 4];
        float4 wb1 = *(const float4*)&w5[c1 * 128 + 64 + j4 * 4];
        float4 c4 = *(const float4*)&cens[p][j4 * 4];
        ab0.x += (wb0.x - wa0.x) * c4.x; ab0.y += (wb0.y - wa0.y) * c4.y;
        ab0.z += (wb0.z - wa0.z) * c4.z; ab0.w += (wb0.w - wa0.w) * c4.w;
        ab1.x += (wb1.x - wa1.x) * c4.x; ab1.y += (wb1.y - wa1.y) * c4.y;
        ab1.z += (wb1.z - wa1.z) * c4.z; ab1.w += (wb1.w - wa1.w) * c4.w;
        #pragma unroll
        for (int k = 0; k < KNN; ++k) {
            float4 f4 = *(const float4*)&feas[p][k][j4 * 4];
            a0[k] += wa0.x * f4.x + wa0.y * f4.y + wa0.z * f4.z + wa0.w * f4.w;
            a1[k] += wa1.x * f4.x + wa1.y * f4.y + wa1.z * f4.z + wa1.w * f4.w;
        }
    }
    const float abase0 = (ab0.x + ab0.y) + (ab0.z + ab0.w);
    const float abase1 = (ab1.x + ab1.y) + (ab1.z + ab1.w);
    const float s5c0 = s5[c0], b5c0 = b5[c0], s5c1 = s5[c1], b5c1 = b5[c1];
    float mx0 = -FLT_MAX, mx1 = -FLT_MAX;
    #pragma unroll
    for (int k = 0; k < KNN; ++k) {
        mx0 = fmaxf(mx0, lrelu((a0[k] + abase0) * s5c0 + b5c0));
        mx1 = fmaxf(mx1, lrelu((a1[k] + abase1) * s5c1 + b5c1));
    }
    outt[(size_t)pn * 64 + c0] = mx0;
    outt[(size_t)pn * 64 + c1] = mx1;
}

// ---------------- label branch: (16) -> 64 ----------------
__global__ __launch_bounds__(64) void catvet_kernel(
    const float* __restrict__ label,
    const float* __restrict__ w7, const float* __restrict__ s7, const float* __restrict__ b7,
    float* __restrict__ catv) {
    const int b = blockIdx.x, c = threadIdx.x;
    float a = 0.f;
    #pragma unroll
    for (int i = 0; i < 16; ++i) a += w7[c * 16 + i] * label[b * 16 + i];
    catv[b * 64 + c] = lrelu(a * s7[c] + b7[c]);
}

// ---------------- w6 transpose: w6t[k][c] = w6[c][k] (one-time, 768 KB) ----------------
__global__ void w6t_kernel(const float* __restrict__ w6, float* __restrict__ w6t) {
    int i = blockIdx.x * 256 + threadIdx.x;
    if (i >= 192 * 1024) return;
    int k = i >> 10, c = i & 1023;
    w6t[i] = w6[c * 192 + k];
}

// ---------------- head weight transposes (one-time, 576 KB total) ----------------
// wp1t[k][o] (k<192,o<256) = wp1[o][k]; wp2t[k][o] = wp2[o][k]; wp3t[k][o] (o<128) = wp3[o][k]
__global__ void wpt_kernel(const float* __restrict__ wp1, const float* __restrict__ wp2,
                           const float* __restrict__ wp3,
                           float* __restrict__ wp1t, float* __restrict__ wp2t,
                           float* __restrict__ wp3t) {
    int i = blockIdx.x * 256 + threadIdx.x;
    if (i < 192 * 256) {
        int k = i >> 8, o = i & 255;
        wp1t[i] = wp1[(size_t)o * 1280 + k];
        return;
    }
    i -= 192 * 256;
    if (i < 256 * 256) {
        int k = i >> 8, o = i & 255;
        wp2t[i] = wp2[(size_t)o * 256 + k];
        return;
    }
    i -= 256 * 256;
    if (i < 256 * 128) {
        int k = i >> 7, o = i & 127;
        wp3t[i] = wp3[(size_t)o * 256 + k];
    }
}

// ---------------- global feature GEMM: raw max_n( w6 . x[n] ) per channel ----------------
constexpr int OPTS = 32;
__global__ __launch_bounds__(256) void out4max_kernel(
    const float* __restrict__ out1t, const float* __restrict__ out2t, const float* __restrict__ out3t,
    const float* __restrict__ w6t, float* __restrict__ partial) {
    const int blk = blockIdx.x;
    const int b   = blk >> 6;
    const int nt  = blk & 63;
    const int t   = threadIdx.x;

    __shared__ float xs[192 * OPTS];
    for (int idx = t; idx < 192 * OPTS; idx += 256) {
        int p = idx / 192, r = idx - p * 192;
        const size_t gp = (size_t)b * NPTS + nt * OPTS + p;
        float val;
        if (r < 64)       val = out1t[gp * 64 + r];
        else if (r < 128) val = out2t[gp * 64 + (r - 64)];
        else              val = out3t[gp * 64 + (r - 128)];
        xs[r * OPTS + p] = val;
    }
    __syncthreads();

    float mx0 = -FLT_MAX, mx1 = -FLT_MAX, mx2 = -FLT_MAX, mx3 = -FLT_MAX;
    #pragma unroll
    for (int pg = 0; pg < OPTS / 16; ++pg) {
        float acc0[16], acc1[16], acc2[16], acc3[16];
        #pragma unroll
        for (int p = 0; p < 16; ++p) { acc0[p] = 0.f; acc1[p] = 0.f; acc2[p] = 0.f; acc3[p] = 0.f; }
        #pragma unroll 2
        for (int k = 0; k < 192; ++k) {
            float4 wv = *(const float4*)&w6t[(size_t)k * 1024 + t * 4];
            const float4* xr4 = (const float4*)&xs[k * OPTS + pg * 16];
            #pragma unroll
            for (int p4 = 0; p4 < 4; ++p4) {
                float4 xv = xr4[p4];
                acc0[p4 * 4 + 0] += wv.x * xv.x; acc0[p4 * 4 + 1] += wv.x * xv.y;
                acc0[p4 * 4 + 2] += wv.x * xv.z; acc0[p4 * 4 + 3] += wv.x * xv.w;
                acc1[p4 * 4 + 0] += wv.y * xv.x; acc1[p4 * 4 + 1] += wv.y * xv.y;
                acc1[p4 * 4 + 2] += wv.y * xv.z; acc1[p4 * 4 + 3] += wv.y * xv.w;
                acc2[p4 * 4 + 0] += wv.z * xv.x; acc2[p4 * 4 + 1] += wv.z * xv.y;
                acc2[p4 * 4 + 2] += wv.z * xv.z; acc2[p4 * 4 + 3] += wv.z * xv.w;
                acc3[p4 * 4 + 0] += wv.w * xv.x; acc3[p4 * 4 + 1] += wv.w * xv.y;
                acc3[p4 * 4 + 2] += wv.w * xv.z; acc3[p4 * 4 + 3] += wv.w * xv.w;
            }
        }
        #pragma unroll
        for (int p = 0; p < 16; ++p) {
            mx0 = fmaxf(mx0, acc0[p]); mx1 = fmaxf(mx1, acc1[p]);
            mx2 = fmaxf(mx2, acc2[p]); mx3 = fmaxf(mx3, acc3[p]);
        }
    }
    float4 o = {mx0, mx1, mx2, mx3};
    *(float4*)&partial[(size_t)blk * 1024 + t * 4] = o;
}

__global__ __launch_bounds__(256) void out4reduce_kernel(
    const float* __restrict__ partial,
    const float* __restrict__ s6, const float* __restrict__ b6,
    float* __restrict__ out4m) {
    const int i = blockIdx.x * 256 + threadIdx.x;
    const int b = i >> 10, c = i & 1023;
    float m = -FLT_MAX;
    for (int nt = 0; nt < 64; ++nt)
        m = fmaxf(m, partial[((size_t)b * 64 + nt) * 1024 + c]);
    out4m[i] = lrelu(m * s6[c] + b6[c]);
}

// ---------------- per-batch head bias: g[b][o] = wp1[o,192:1280] . [out4m;catv] ----------------
__global__ __launch_bounds__(256) void gbias_kernel(
    const float* __restrict__ out4m, const float* __restrict__ catv,
    const float* __restrict__ wp1, float* __restrict__ g) {
    const int b = blockIdx.x, t = threadIdx.x;
    __shared__ float v[1088];
    for (int i = t; i < 1088; i += 256)
        v[i] = (i < 1024) ? out4m[(size_t)b * 1024 + i] : catv[(size_t)b * 64 + (i - 1024)];
    __syncthreads();
    const float* w = wp1 + (size_t)t * 1280 + 192;
    float4 s4 = {0.f, 0.f, 0.f, 0.f};
    for (int i = 0; i < 272; ++i) {
        float4 wv = *(const float4*)&w[i * 4];
        float4 vv = *(const float4*)&v[i * 4];
        s4.x += wv.x * vv.x; s4.y += wv.y * vv.y; s4.z += wv.z * vv.z; s4.w += wv.w * vv.w;
    }
    g[(size_t)b * 256 + t] = (s4.x + s4.y) + (s4.z + s4.w);
}

// ---------------- per-point head v3 (HP=32, transposed weights, coalesced f4 staging) ----------------
constexpr int HP = 32;   // points per block
constexpr int KC = 16;   // k-chunk

__global__ __launch_bounds__(256) void head_kernel(
    const float* __restrict__ out1t, const float* __restrict__ out2t, const float* __restrict__ out3t,
    const float* __restrict__ g,
    const float* __restrict__ wp1t, const float* __restrict__ sp1, const float* __restrict__ bp1,
    const float* __restrict__ wp2t, const float* __restrict__ sp2, const float* __restrict__ bp2,
    const float* __restrict__ wp3t, const float* __restrict__ sp3, const float* __restrict__ bp3,
    const float* __restrict__ wp4, float* __restrict__ out) {
    const int p0 = blockIdx.x * HP;
    const int b  = p0 >> 11;
    const int t  = threadIdx.x;

    __shared__ float smA[8192];      // xs[192][32] then t2s[256][32]
    __shared__ float smB[8192];      // t1s[256][32] then t3s[128][32]
    __shared__ __align__(16) float smW[KC * 256];  // weight chunk, k-major

    // stage x (192 per-point channels), layout xs[k][p]
    for (int e = t; e < 192 * HP; e += 256) {
        int p = e / 192, k = e - p * 192;
        float val;
        if (k < 64)       val = out1t[((size_t)(p0 + p)) * 64 + k];
        else if (k < 128) val = out2t[((size_t)(p0 + p)) * 64 + (k - 64)];
        else              val = out3t[((size_t)(p0 + p)) * 64 + (k - 128)];
        smA[k * HP + p] = val;
    }

    const int og = t & 31;   // 8 outs each
    const int pg = t >> 5;   // 4 points each (pg*4 .. pg*4+3)

    // ---- layer 1: 192 -> 256, acc init = per-batch g ----
    float acc[4][8];
    #pragma unroll
    for (int i = 0; i < 8; ++i) {
        float gv = g[(size_t)b * 256 + og * 8 + i];
        acc[0][i] = gv; acc[1][i] = gv; acc[2][i] = gv; acc[3][i] = gv;
    }
    for (int kc = 0; kc < 192 / KC; ++kc) {
        __syncthreads();
        {   // coalesced f4 staging: 1024 f4 for this chunk
            const float4* wsrc = (const float4*)(wp1t + (size_t)kc * KC * 256);
            float4* wdst = (float4*)smW;
            #pragma unroll
            for (int r = 0; r < 4; ++r) wdst[t + r * 256] = wsrc[t + r * 256];
        }
        __syncthreads();
        #pragma unroll 4
        for (int kk = 0; kk < KC; ++kk) {
            int k = kc * KC + kk;
            float4 xv = *(const float4*)&smA[k * HP + pg * 4];
            float4 w0 = *(const float4*)&smW[kk * 256 + og * 8];
            float4 w1v = *(const float4*)&smW[kk * 256 + og * 8 + 4];
            float wv[8] = {w0.x, w0.y, w0.z, w0.w, w1v.x, w1v.y, w1v.z, w1v.w};
            #pragma unroll
            for (int i = 0; i < 8; ++i) {
                acc[0][i] += xv.x * wv[i];
                acc[1][i] += xv.y * wv[i];
                acc[2][i] += xv.z * wv[i];
                acc[3][i] += xv.w * wv[i];
            }
        }
    }
    __syncthreads();   // xs reads done before... (t1s writes go to smB, safe anyway)
    #pragma unroll
    for (int i = 0; i < 8; ++i) {
        int o = og * 8 + i;
        float sc = sp1[o], bc = bp1[o];
        smB[o * HP + pg * 4 + 0] = lrelu(acc[0][i] * sc + bc);
        smB[o * HP + pg * 4 + 1] = lrelu(acc[1][i] * sc + bc);
        smB[o * HP + pg * 4 + 2] = lrelu(acc[2][i] * sc + bc);
        smB[o * HP + pg * 4 + 3] = lrelu(acc[3][i] * sc + bc);
    }

    // ---- layer 2: 256 -> 256 (reads t1s=smB, writes t2s=smA) ----
    float acc2[4][8];
    #pragma unroll
    for (int i = 0; i < 8; ++i) { acc2[0][i] = 0.f; acc2[1][i] = 0.f; acc2[2][i] = 0.f; acc2[3][i] = 0.f; }
    for (int kc = 0; kc < 256 / KC; ++kc) {
        __syncthreads();
        {
            const float4* wsrc = (const float4*)(wp2t + (size_t)kc * KC * 256);
            float4* wdst = (float4*)smW;
            #pragma unroll
            for (int r = 0; r < 4; ++r) wdst[t + r * 256] = wsrc[t + r * 256];
        }
        __syncthreads();
        #pragma unroll 4
        for (int kk = 0; kk < KC; ++kk) {
            int k = kc * KC + kk;
            float4 xv = *(const float4*)&smB[k * HP + pg * 4];
            float4 w0 = *(const float4*)&smW[kk * 256 + og * 8];
            float4 w1v = *(const float4*)&smW[kk * 256 + og * 8 + 4];
            float wv[8] = {w0.x, w0.y, w0.z, w0.w, w1v.x, w1v.y, w1v.z, w1v.w};
            #pragma unroll
            for (int i = 0; i < 8; ++i) {
                acc2[0][i] += xv.x * wv[i];
                acc2[1][i] += xv.y * wv[i];
                acc2[2][i] += xv.z * wv[i];
                acc2[3][i] += xv.w * wv[i];
            }
        }
    }
    __syncthreads();   // all t1s reads done; xs (smA) dead -> write t2s
    #pragma unroll
    for (int i = 0; i < 8; ++i) {
        int o = og * 8 + i;
        float sc = sp2[o], bc = bp2[o];
        smA[o * HP + pg * 4 + 0] = lrelu(acc2[0][i] * sc + bc);
        smA[o * HP + pg * 4 + 1] = lrelu(acc2[1][i] * sc + bc);
        smA[o * HP + pg * 4 + 2] = lrelu(acc2[2][i] * sc + bc);
        smA[o * HP + pg * 4 + 3] = lrelu(acc2[3][i] * sc + bc);
    }

    // ---- layer 3: 256 -> 128 (reads t2s=smA, writes t3s=smB) ----
    const int og3 = t & 15;   // 8 outs each
    const int pg3 = t >> 4;   // 2 points each (pg3, pg3+16)
    float acc3[2][8];
    #pragma unroll
    for (int i = 0; i < 8; ++i) { acc3[0][i] = 0.f; acc3[1][i] = 0.f; }
    for (int kc = 0; kc < 256 / KC; ++kc) {
        __syncthreads();
        {
            const float4* wsrc = (const float4*)(wp3t + (size_t)kc * KC * 128);
            float4* wdst = (float4*)smW;
            #pragma unroll
            for (int r = 0; r < 2; ++r) wdst[t + r * 256] = wsrc[t + r * 256];
        }
        __syncthreads();
        #pragma unroll 4
        for (int kk = 0; kk < KC; ++kk) {
            int k = kc * KC + kk;
            float xv0 = smA[k * HP + pg3];
            float xv1 = smA[k * HP + 16 + pg3];
            float4 w0 = *(const float4*)&smW[kk * 128 + og3 * 8];
            float4 w1v = *(const float4*)&smW[kk * 128 + og3 * 8 + 4];
            float wv[8] = {w0.x, w0.y, w0.z, w0.w, w1v.x, w1v.y, w1v.z, w1v.w};
            #pragma unroll
            for (int i = 0; i < 8; ++i) {
                acc3[0][i] += xv0 * wv[i];
                acc3[1][i] += xv1 * wv[i];
            }
        }
    }
    __syncthreads();   // t1s fully consumed; safe to write t3s
    #pragma unroll
    for (int i = 0; i < 8; ++i) {
        int o = og3 * 8 + i;
        float sc = sp3[o], bc = bp3[o];
        smB[o * HP + pg3]      = lrelu(acc3[0][i] * sc + bc);
        smB[o * HP + 16 + pg3] = lrelu(acc3[1][i] * sc + bc);
    }
    __syncthreads();

    // ---- layer 4: 128 -> 6 ----
    if (t < HP * 6) {
        int p = t / 6, o = t - p * 6;
        float4 s4 = {0.f, 0.f, 0.f, 0.f};
        for (int k4 = 0; k4 < 32; ++k4) {
            float4 wv = *(const float4*)&wp4[o * 128 + k4 * 4];
            s4.x += wv.x * smB[(k4 * 4 + 0) * HP + p];
            s4.y += wv.y * smB[(k4 * 4 + 1) * HP + p];
            s4.z += wv.z * smB[(k4 * 4 + 2) * HP + p];
            s4.w += wv.w * smB[(k4 * 4 + 3) * HP + p];
        }
        out[((size_t)(p0 + p)) * 6 + o] = (s4.x + s4.y) + (s4.z + s4.w);
    }
}

extern "C" void kernel_launch(void* const* d_in, const int* in_sizes, int n_in,
                              void* d_out, int out_size, void* d_ws, size_t ws_size,
                              hipStream_t stream) {
    const float* points = (const float*)d_in[0];
    const float* label  = (const float*)d_in[1];
    const float* w1  = (const float*)d_in[2];
    const float* s1  = (const float*)d_in[3];
    const float* b1  = (const float*)d_in[4];
    const float* w2  = (const float*)d_in[5];
    const float* s2  = (const float*)d_in[6];
    const float* b2  = (const float*)d_in[7];
    const float* w3  = (const float*)d_in[8];
    const float* s3  = (const float*)d_in[9];
    const float* b3  = (const float*)d_in[10];
    const float* w4  = (const float*)d_in[11];
    const float* s4  = (const float*)d_in[12];
    const float* b4  = (const float*)d_in[13];
    const float* w5  = (const float*)d_in[14];
    const float* s5  = (const float*)d_in[15];
    const float* b5  = (const float*)d_in[16];
    const float* w6  = (const float*)d_in[17];
    const float* s6  = (const float*)d_in[18];
    const float* b6  = (const float*)d_in[19];
    const float* w7  = (const float*)d_in[20];
    const float* s7  = (const float*)d_in[21];
    const float* b7  = (const float*)d_in[22];
    const float* wp1 = (const float*)d_in[23];
    const float* sp1 = (const float*)d_in[24];
    const float* bp1 = (const float*)d_in[25];
    const float* wp2 = (const float*)d_in[26];
    const float* sp2 = (const float*)d_in[27];
    const float* bp2 = (const float*)d_in[28];
    const float* wp3 = (const float*)d_in[29];
    const float* sp3 = (const float*)d_in[30];
    const float* bp3 = (const float*)d_in[31];
    const float* wp4 = (const float*)d_in[32];

    float* ws = (float*)d_ws;
    size_t off = 0;
    auto alloc = [&](size_t nf) { float* p = ws + off; off += nf; return p; };
    float* out1t = alloc((size_t)BATCH * NPTS * 64);
    float* out2t = alloc((size_t)BATCH * NPTS * 64);
    float* out3t = alloc((size_t)BATCH * NPTS * 64);
    float* sqb   = alloc((size_t)BATCH * NPTS);
    float* out4m = alloc((size_t)BATCH * 1024);
    float* catv  = alloc((size_t)BATCH * 64);
    float* gb    = alloc((size_t)BATCH * 256);
    float* w6t   = alloc((size_t)192 * 1024);
    float* part  = alloc((size_t)512 * 1024);
    float* wp1t  = alloc((size_t)192 * 256);
    float* wp2t  = alloc((size_t)256 * 256);
    float* wp3t  = alloc((size_t)256 * 128);
    int* idx1 = (int*)alloc((size_t)BATCH * NPTS * KNN);
    int* idx2 = (int*)alloc((size_t)BATCH * NPTS * KNN);
    int* idx3 = (int*)alloc((size_t)BATCH * NPTS * KNN);

    const int BN = BATCH * NPTS;
    const int sqBlocks = (BN + 255) / 256;

    // one-time weight transposes (depend only on inputs)
    w6t_kernel<<<(192 * 1024 + 255) / 256, 256, 0, stream>>>(w6, w6t);
    wpt_kernel<<<(147456 + 255) / 256, 256, 0, stream>>>(wp1, wp2, wp3, wp1t, wp2t, wp3t);

    // stage 1
    sq_kernel<3><<<sqBlocks, 256, 0, stream>>>(points, sqb);
    knn3_kernel<<<BN, 64, 0, stream>>>(points, sqb, idx1);
    edgeconv1_kernel<<<BN / 8, 256, 0, stream>>>(points, idx1, w1, s1, b1, w2, s2, b2, out1t);

    // stage 2
    sq64_kernel<<<sqBlocks, 256, 0, stream>>>(out1t, sqb);
    knn64_kernel<<<BN / 8, 256, 0, stream>>>(out1t, sqb, idx2);
    edgeconv2_kernel<<<BN / 8, 256, 0, stream>>>(out1t, idx2, w3, s3, b3, w4, s4, b4, out2t);

    // stage 3
    sq64_kernel<<<sqBlocks, 256, 0, stream>>>(out2t, sqb);
    knn64_kernel<<<BN / 8, 256, 0, stream>>>(out2t, sqb, idx3);
    edgeconv3_kernel<<<BN / 8, 256, 0, stream>>>(out2t, idx3, w5, s5, b5, out3t);

    // global branches
    catvet_kernel<<<BATCH, 64, 0, stream>>>(label, w7, s7, b7, catv);
    out4max_kernel<<<512, 256, 0, stream>>>(out1t, out2t, out3t, w6t, part);
    out4reduce_kernel<<<BATCH * 1024 / 256, 256, 0, stream>>>(part, s6, b6, out4m);
    gbias_kernel<<<BATCH, 256, 0, stream>>>(out4m, catv, wp1, gb);

    // head
    head_kernel<<<BN / HP, 256, 0, stream>>>(out1t, out2t, out3t, gb,
                                             wp1t, sp1, bp1, wp2t, sp2, bp2, wp3t, sp3, bp3,
                                             wp4, (float*)d_out);
}